// Round 1
// baseline (122.526 us; speedup 1.0000x reference)
//
#include <hip/hip_runtime.h>
#include <math.h>

#define OBS 8
#define ACT 4
#define DIN 12
#define NTRAIN 128
#define BATCH 8

// workspace layout (floats):
//  jm : BATCH*DIN        @ 0      (96)
//  jv : BATCH*DIN*DIN    @ 96     (1152)
//  pm : BATCH*OBS        @ 1248   (64)
//  cc : BATCH*DIN*OBS    @ 1312   (768)   cc[b][d][e]
//  mn : BATCH*OBS*OBS    @ 2080   (512)   main[b][a][c]
//  tr : BATCH*OBS        @ 2592   (64)    tr[b][e]
#define WS_JM 0
#define WS_JV 96
#define WS_PM 1248
#define WS_CC 1312
#define WS_MN 2080
#define WS_TR 2592

// ---------------------------------------------------------------------------
// Kernel A: joint_mean + joint_var per batch
// ---------------------------------------------------------------------------
__global__ void k_setup(const float* __restrict__ m_x, const float* __restrict__ s_x,
                        const float* __restrict__ m_u, const float* __restrict__ s_u,
                        const float* __restrict__ c_xu, float* __restrict__ ws) {
    int b = blockIdx.x;
    int t = threadIdx.x;
    float* jm = ws + WS_JM + b * DIN;
    float* jv = ws + WS_JV + b * DIN * DIN;
    if (t < DIN) jm[t] = (t < OBS) ? m_x[b * OBS + t] : m_u[b * ACT + t - OBS];
    if (t < DIN * DIN) {
        int r = t / DIN, c = t % DIN;
        float v;
        if (r < OBS && c < OBS) {
            v = s_x[(b * OBS + r) * OBS + c];
        } else if (r < OBS) { // upper-right: s_ = s_x @ c_xu
            float acc = 0.f;
            for (int k = 0; k < OBS; k++)
                acc += s_x[(b * OBS + r) * OBS + k] * c_xu[(b * OBS + k) * ACT + (c - OBS)];
            v = acc;
        } else if (c < OBS) { // lower-left: s_^T
            float acc = 0.f;
            for (int k = 0; k < OBS; k++)
                acc += s_x[(b * OBS + c) * OBS + k] * c_xu[(b * OBS + k) * ACT + (r - OBS)];
            v = acc;
        } else {
            v = s_u[(b * ACT + r - OBS) * ACT + (c - OBS)];
        }
        jv[t] = v;
    }
}

// ---------------------------------------------------------------------------
// Kernel B: per (b,e) GP predictive mean + cross-cov. 64 blocks x 128 threads.
// ---------------------------------------------------------------------------
__global__ void __launch_bounds__(128) k_gp(const float* __restrict__ X,
                                            const float* __restrict__ ls,
                                            const float* __restrict__ vars,
                                            const float* __restrict__ beta,
                                            float* __restrict__ ws) {
    int blk = blockIdx.x;
    int b = blk / OBS, e = blk % OBS;
    int tid = threadIdx.x;
    __shared__ float aug[DIN][25];   // [A | A^-1] augmented, padded
    __shared__ float ivls[DIN], mu[DIN], shf[DIN];
    __shared__ float sh_pivinv, sh_det;
    __shared__ float red[2][13];
    const float* jm = ws + WS_JM + b * DIN;
    const float* jv = ws + WS_JV + b * DIN * DIN;
    if (tid < DIN) { ivls[tid] = 1.0f / ls[e * DIN + tid]; mu[tid] = jm[tid]; }
    if (tid == 0) sh_det = 1.0f;
    __syncthreads();
    for (int t = tid; t < DIN * 24; t += 128) {
        int r = t / 24, c = t % 24;
        aug[r][c] = (c < DIN) ? (ivls[r] * jv[r * DIN + c] * ivls[c] + (r == c ? 1.0f : 0.0f))
                              : ((c - DIN) == r ? 1.0f : 0.0f);
    }
    __syncthreads();
    // Gauss-Jordan (no pivoting; B = I + PSD-scaled is safe)
    for (int k = 0; k < DIN; k++) {
        if (tid == 0) { float p = aug[k][k]; sh_det *= p; sh_pivinv = 1.0f / p; }
        __syncthreads();
        if (tid < 24) aug[k][tid] *= sh_pivinv;
        if (tid >= 32 && tid < 32 + DIN) { int r = tid - 32; shf[r] = aug[r][k]; }
        __syncthreads();
        for (int t = tid; t < DIN * 24; t += 128) {
            int r = t / 24, c = t % 24;
            if (r != k) aug[r][c] -= shf[r] * aug[k][c];
        }
        __syncthreads();
    }
    // one thread per training point
    int n = tid;
    float x[DIN];
    {
        const float4* xr = (const float4*)(X + n * DIN);
        float4 x0 = xr[0], x1 = xr[1], x2 = xr[2];
        x[0]=x0.x; x[1]=x0.y; x[2]=x0.z; x[3]=x0.w;
        x[4]=x1.x; x[5]=x1.y; x[6]=x1.z; x[7]=x1.w;
        x[8]=x2.x; x[9]=x2.y; x[10]=x2.z; x[11]=x2.w;
    }
    float iN[DIN], tv[DIN];
    #pragma unroll
    for (int d = 0; d < DIN; d++) iN[d] = (x[d] - mu[d]) * ivls[d];
    #pragma unroll
    for (int d = 0; d < DIN; d++) {
        float acc = 0.f;
        #pragma unroll
        for (int cl = 0; cl < DIN; cl++) acc += aug[d][12 + cl] * iN[cl];
        tv[d] = acc;
    }
    float q = 0.f;
    #pragma unroll
    for (int d = 0; d < DIN; d++) q += iN[d] * tv[d];
    float lb = __expf(-0.5f * q) * beta[e * NTRAIN + n];
    float vals[13];
    vals[0] = lb;
    #pragma unroll
    for (int d = 0; d < DIN; d++) vals[1 + d] = tv[d] * ivls[d] * lb;
    // block reduce: butterfly within wave (64), then combine the 2 waves
    #pragma unroll
    for (int v = 0; v < 13; v++) {
        #pragma unroll
        for (int off = 32; off >= 1; off >>= 1) vals[v] += __shfl_xor(vals[v], off, 64);
    }
    int wv = tid >> 6, lane = tid & 63;
    if (lane == 0) {
        #pragma unroll
        for (int v = 0; v < 13; v++) red[wv][v] = vals[v];
    }
    __syncthreads();
    if (tid == 0) {
        float cnorm = vars[e] / sqrtf(sh_det);
        ws[WS_PM + b * OBS + e] = cnorm * (red[0][0] + red[1][0]);
        for (int d = 0; d < DIN; d++)
            ws[WS_CC + (b * DIN + d) * OBS + e] = cnorm * (red[0][1 + d] + red[1][1 + d]);
    }
}

// ---------------------------------------------------------------------------
// Kernel C: per (b, a, c) pair -> main[b][a][c]; diag pairs also trace.
// 512 blocks x 256 threads. Q_ij = c_ab * exp(base_i + base_j + g_i . v_j)
// ---------------------------------------------------------------------------
__global__ void __launch_bounds__(256) k_pair(const float* __restrict__ X,
                                              const float* __restrict__ ls,
                                              const float* __restrict__ vars,
                                              const float* __restrict__ beta,
                                              const float* __restrict__ invK,
                                              float* __restrict__ ws) {
    int blk = blockIdx.x;
    int b = blk >> 6, a = (blk >> 3) & 7, c = blk & 7;
    int tid = threadIdx.x;
    __shared__ float aug[DIN][25];
    __shared__ float jvs[DIN * DIN];
    __shared__ float mu[DIN], Lam[DIN], wsum[DIN], inva[DIN], invc[DIN], isum_s[DIN];
    __shared__ float shf[DIN];
    __shared__ float sh_pivinv, sh_det, sh_cab;
    __shared__ float g[NTRAIN][24];     // rows 96B -> 16B aligned
    __shared__ float basei[NTRAIN], wa[NTRAIN];
    __shared__ float red[4][2];
    const float* jm = ws + WS_JM + b * DIN;
    const float* jv = ws + WS_JV + b * DIN * DIN;
    for (int t = tid; t < DIN * DIN; t += 256) jvs[t] = jv[t];
    if (tid < DIN) {
        float la = ls[a * DIN + tid]; la *= la;
        float lc = ls[c * DIN + tid]; lc *= lc;
        float ia = 1.0f / la, ic = 1.0f / lc;
        inva[tid] = ia; invc[tid] = ic;
        wsum[tid] = 1.0f / (la + lc);
        float is = ia + ic;
        isum_s[tid] = is; Lam[tid] = 1.0f / is;
        mu[tid] = jm[tid];
    }
    if (tid == 0) sh_det = 1.0f;
    __syncthreads();
    for (int t = tid; t < DIN * 24; t += 256) {
        int r = t / 24, cl = t % 24;
        aug[r][cl] = (cl < DIN) ? (jvs[r * DIN + cl] + (r == cl ? Lam[r] : 0.0f))
                                : ((cl - DIN) == r ? 1.0f : 0.0f);
    }
    __syncthreads();
    for (int k = 0; k < DIN; k++) {
        if (tid == 0) { float p = aug[k][k]; sh_det *= p; sh_pivinv = 1.0f / p; }
        __syncthreads();
        if (tid < 24) aug[k][tid] *= sh_pivinv;
        if (tid >= 32 && tid < 32 + DIN) { int r = tid - 32; shf[r] = aug[r][k]; }
        __syncthreads();
        for (int t = tid; t < DIN * 24; t += 256) {
            int r = t / 24, cl = t % 24;
            if (r != k) aug[r][cl] -= shf[r] * aug[k][cl];
        }
        __syncthreads();
    }
    if (tid == 0) {
        // det(R_ab) = det(M) * prod(inv_sum)  since R = M @ diag(inv_sum)
        float dr = sh_det;
        for (int d = 0; d < DIN; d++) dr *= isum_s[d];
        sh_cab = vars[a] * vars[c] / sqrtf(dr);
    }
    // i-side into shared (threads 0..127)
    if (tid < NTRAIN) {
        int i = tid;
        float x[DIN];
        const float4* xr = (const float4*)(X + i * DIN);
        float4 x0 = xr[0], x1 = xr[1], x2 = xr[2];
        x[0]=x0.x; x[1]=x0.y; x[2]=x0.z; x[3]=x0.w;
        x[4]=x1.x; x[5]=x1.y; x[6]=x1.z; x[7]=x1.w;
        x[8]=x2.x; x[9]=x2.y; x[10]=x2.z; x[11]=x2.w;
        float r[DIN]; float e1 = 0.f;
        #pragma unroll
        for (int d = 0; d < DIN; d++) {
            r[d] = Lam[d] * x[d] * inva[d] - mu[d];
            e1 += wsum[d] * x[d] * x[d];
            g[i][d] = wsum[d] * x[d];
        }
        float alpha = 0.f;
        #pragma unroll
        for (int d = 0; d < DIN; d++) {
            float u = 0.f;
            #pragma unroll
            for (int cl = 0; cl < DIN; cl++) u += aug[d][12 + cl] * r[cl];
            g[i][12 + d] = -u;          // cross term: -(W r_i) . q_j
            alpha += r[d] * u;
        }
        basei[i] = -0.5f * e1 - 0.5f * alpha;
        wa[i] = beta[a * NTRAIN + i];
    }
    // j-side in registers (all threads; j = tid & 127)
    int j = tid & 127;
    float v[24], basej, wc;
    {
        float x[DIN];
        const float4* xr = (const float4*)(X + j * DIN);
        float4 x0 = xr[0], x1 = xr[1], x2 = xr[2];
        x[0]=x0.x; x[1]=x0.y; x[2]=x0.z; x[3]=x0.w;
        x[4]=x1.x; x[5]=x1.y; x[6]=x1.z; x[7]=x1.w;
        x[8]=x2.x; x[9]=x2.y; x[10]=x2.z; x[11]=x2.w;
        float q[DIN]; float e1 = 0.f;
        #pragma unroll
        for (int d = 0; d < DIN; d++) {
            v[d] = x[d];
            float qd = Lam[d] * x[d] * invc[d];
            q[d] = qd; v[12 + d] = qd;
            e1 += wsum[d] * x[d] * x[d];
        }
        float bq = 0.f;
        #pragma unroll
        for (int d = 0; d < DIN; d++) {
            float u = 0.f;
            #pragma unroll
            for (int cl = 0; cl < DIN; cl++) u += aug[d][12 + cl] * q[cl];
            bq += q[d] * u;
        }
        basej = -0.5f * e1 - 0.5f * bq;
        wc = beta[c * NTRAIN + j];
    }
    __syncthreads();
    // main loop: 64 entries/thread, i wave-uniform (broadcast LDS reads)
    float accm = 0.f, acct = 0.f;
    bool diag = (a == c);
    const float* Ka = invK + a * NTRAIN * NTRAIN;
    int ip = tid >> 7;
    #pragma unroll 4
    for (int k = 0; k < 64; k++) {
        int i = ip + 2 * k;
        float s = basei[i] + basej;
        #pragma unroll
        for (int d = 0; d < 24; d++) s += g[i][d] * v[d];
        float qv = __expf(s);
        accm += wa[i] * wc * qv;
        if (diag) acct += Ka[i * NTRAIN + j] * qv;  // invK fp-exact symmetric
    }
    #pragma unroll
    for (int off = 32; off >= 1; off >>= 1) {
        accm += __shfl_xor(accm, off, 64);
        acct += __shfl_xor(acct, off, 64);
    }
    int wv = tid >> 6, lane = tid & 63;
    if (lane == 0) { red[wv][0] = accm; red[wv][1] = acct; }
    __syncthreads();
    if (tid == 0) {
        float m = (red[0][0] + red[1][0] + red[2][0] + red[3][0]) * sh_cab;
        ws[WS_MN + b * 64 + a * 8 + c] = m;
        if (diag) {
            float t = (red[0][1] + red[1][1] + red[2][1] + red[3][1]) * sh_cab;
            ws[WS_TR + b * 8 + a] = t;
        }
    }
}

// ---------------------------------------------------------------------------
// Kernel D: epilogue / assembly. 8 blocks x 64 threads.
// ---------------------------------------------------------------------------
__global__ void k_final(const float* __restrict__ m_x, const float* __restrict__ s_x,
                        const float* __restrict__ vars, const float* __restrict__ noises,
                        const float* __restrict__ ws, float* __restrict__ out) {
    int b = blockIdx.x, t = threadIdx.x;
    __shared__ float pm[OBS];
    const float* jv = ws + WS_JV + b * DIN * DIN;
    const float* cc = ws + WS_CC + b * DIN * OBS;
    const float* mn = ws + WS_MN + b * 64;
    const float* tr = ws + WS_TR + b * 8;
    if (t < OBS) {
        float p = ws[WS_PM + b * OBS + t];
        pm[t] = p;
        out[b * OBS + t] = m_x[b * OBS + t] + p;   // m_out
    }
    __syncthreads();
    int r = t >> 3, cl = t & 7;
    float Prc = mn[r * 8 + cl], Pcr = mn[cl * 8 + r];
    if (r == cl) {
        float dc = vars[r] - tr[r] + noises[r];
        Prc += dc; Pcr += dc;
    }
    Prc -= pm[r] * pm[cl];
    Pcr -= pm[cl] * pm[r];
    float Psym = 0.5f * (Prc + Pcr);
    float cxf = 0.f, cxfT = 0.f;
    #pragma unroll
    for (int d = 0; d < DIN; d++) {
        cxf  += jv[r * DIN + d] * cc[d * OBS + cl];   // upper @ cross_cov
        cxfT += jv[cl * DIN + d] * cc[d * OBS + r];   // its transpose
    }
    float S = s_x[b * 64 + r * 8 + cl] + Psym + cxf + cxfT;
    if (r == cl) S += 1e-8f;
    out[64 + b * 64 + r * 8 + cl] = S;               // s_out
}

// ---------------------------------------------------------------------------
extern "C" void kernel_launch(void* const* d_in, const int* in_sizes, int n_in,
                              void* d_out, int out_size, void* d_ws, size_t ws_size,
                              hipStream_t stream) {
    const float* m_x    = (const float*)d_in[0];
    const float* s_x    = (const float*)d_in[1];
    const float* m_u    = (const float*)d_in[2];
    const float* s_u    = (const float*)d_in[3];
    const float* c_xu   = (const float*)d_in[4];
    const float* X      = (const float*)d_in[5];
    const float* ls     = (const float*)d_in[6];
    const float* vars   = (const float*)d_in[7];
    const float* noises = (const float*)d_in[8];
    const float* invK   = (const float*)d_in[9];
    const float* beta   = (const float*)d_in[10];
    float* out = (float*)d_out;
    float* ws  = (float*)d_ws;

    k_setup<<<BATCH, 192, 0, stream>>>(m_x, s_x, m_u, s_u, c_xu, ws);
    k_gp<<<BATCH * OBS, 128, 0, stream>>>(X, ls, vars, beta, ws);
    k_pair<<<BATCH * OBS * OBS, 256, 0, stream>>>(X, ls, vars, beta, invK, ws);
    k_final<<<BATCH, 64, 0, stream>>>(m_x, s_x, vars, noises, ws, out);
}